// Round 12
// baseline (139.880 us; speedup 1.0000x reference)
//
#include <hip/hip_runtime.h>
#include <hip/hip_bf16.h>

typedef _Float16 half8 __attribute__((ext_vector_type(8)));
typedef __fp16 fp16x2 __attribute__((ext_vector_type(2)));
typedef float floatx4 __attribute__((ext_vector_type(4)));

__device__ __forceinline__ uint2 pkh4(float4 v) {
  union { fp16x2 h2[2]; uint2 u; } pk;
  pk.h2[0] = __builtin_amdgcn_cvt_pkrtz(v.x, v.y);
  pk.h2[1] = __builtin_amdgcn_cvt_pkrtz(v.z, v.w);
  return pk.u;
}

__device__ __forceinline__ int c1dw_calc(int mt, int l15, int l4) {
  int m = mt * 16 + l15; if (m > 675) m = 675;
  int img = m / 169, rem = m - img * 169, wr = rem / 13, wc = rem - wr * 13;
  int rowa = img * 28 + 2 * wr + 2 * l4; if (rowa > 110) rowa = 110;
  return rowa * 20 + wc;
}
__device__ __forceinline__ int c2ba_calc(int mt, int l15) {
  int w = mt * 4 + (l15 >> 2), q = l15 & 3;
  int img = w / 25, rem = w - img * 25, wr = rem / 5, wc = rem - wr * 5;
  int r = 2 * wr + (q >> 1), c = 2 * wc + (q & 1);
  return (img * 169 + r * 13 + c) * 16;
}
__device__ __forceinline__ int c2st_calc(int mt, int l15, int l4) {
  int w2 = mt * 4 + l4, i2 = w2 / 25, rm2 = w2 - i2 * 25;
  return i2 * 424 + l15 * 25 + rm2;
}

// LeNet fwd, all-MFMA convs, window-ordered M. Named-scalar hoisted indices
// (no arrays -> no scratch). 16 img / 512-thr block, 1024 blocks, 4 blk/CU.
__global__ __launch_bounds__(512) void lenet_mfma5(
    const float* __restrict__ X,
    const float* __restrict__ W1, const float* __restrict__ B1,
    const float* __restrict__ W2, const float* __restrict__ B2,
    const float* __restrict__ FW, const float* __restrict__ FB,
    const float* __restrict__ F2W, const float* __restrict__ F2B,
    const float* __restrict__ F3W, const float* __restrict__ F3B,
    float* __restrict__ OUT) {
  __shared__ __align__(16) _Float16 p2h[16 * 424];  // pool2 [16][424], 400.. zero; h1f/h2f alias
  __shared__ __align__(16) char region[20224];      // conv: xs f16[4][28][40] + p1f f16[704][8] | fc: w2sf[64][136]+w3sf[10][72]
  __shared__ __align__(16) _Float16 w2L[16 * 104];  // conv2 B [oc][k=tap*8+ic] zero-pad
  __shared__ __align__(16) _Float16 c1B[1280];      // conv1 B 2x[16][40]
  __shared__ float bc1L[8], bc2L[16], fbL[128], f2bL[64], f3bL[16];

  _Float16* xs = (_Float16*)region;                 // [4][28][40]
  _Float16* p1f = (_Float16*)(region + 8960);       // [704][8]
  _Float16* w2sf = (_Float16*)region;               // [64][136]
  _Float16* w3sf = (_Float16*)(region + 17408);     // [10][72]
  _Float16* h1f = p2h;                              // [16][136]
  float* h2f = (float*)((char*)p2h + 6656);         // [16][68]

  const int tid = threadIdx.x;
  const int wave = tid >> 6, lane = tid & 63, l15 = lane & 15, l4 = lane >> 4;
  const int m16 = blockIdx.x * 16;
  const float4* X4 = (const float4*)X;

  // ---- one-time staging ----
  if (tid < 8) bc1L[tid] = B1[tid];
  else if (tid < 24) bc2L[tid - 8] = B2[tid - 8];
  else if (tid < 152) fbL[tid - 24] = FB[tid - 24];
  else if (tid < 216) f2bL[tid - 152] = F2B[tid - 152];
  else if (tid < 226) f3bL[tid - 216] = F3B[tid - 216];

  for (int i = tid; i < 1664; i += 512) {           // conv2 B
    int oc = i / 104, k = i % 104;
    _Float16 v = (_Float16)0.f;
    if (k < 72) { int tap = k >> 3, ic = k & 7; v = (_Float16)W2[(oc * 8 + ic) * 9 + tap]; }
    w2L[i] = v;
  }
  for (int i = tid; i < 1280; i += 512) {           // conv1 B (2 mats)
    int mat = i / 640, r = i % 640, n = r / 40, k = r % 40;
    float v = 0.f;
    if (k < 16) {
      int q = mat * 2 + (n >> 3), ch = n & 7;
      int uu = (k >> 2) - (q >> 1), vv = (k & 3) - (q & 1);
      if (uu >= 0 && uu < 3 && vv >= 0 && vv < 3) v = W1[ch * 9 + uu * 3 + vv];
    }
    c1B[i] = (_Float16)v;
  }
  if (tid < 384) { int rr = tid / 24; p2h[rr * 424 + 400 + tid % 24] = (_Float16)0.f; }

  // ---- prefetch indices (named scalars) + sb=0 image load ----
  int pfg0, pfl0, pfg1, pfl1;
  {
    int i = tid, img = i / 196, f = i % 196, row = f / 7, fq = f % 7;
    pfg0 = (m16 + img) * 196 + f;
    pfl0 = (img * 28 + row) * 40 + fq * 4;
    int i1 = tid + 512; int i1c = (i1 < 784) ? i1 : 783;
    int img1 = i1c / 196, f1 = i1c % 196, row1 = f1 / 7, fq1 = f1 % 7;
    pfg1 = (m16 + img1) * 196 + f1;
    pfl1 = (img1 * 28 + row1) * 40 + fq1 * 4;
    *(uint2*)(xs + pfl0) = pkh4(X4[pfg0]);
    if (i1 < 784) *(uint2*)(xs + pfl1) = pkh4(X4[pfg1]);
  }

  // ---- conv per-iter indices: NAMED SCALARS (registers, no scratch) ----
  const int dw0 = c1dw_calc(wave,      l15, l4);
  const int dw1 = c1dw_calc(wave + 8,  l15, l4);
  const int dw2 = c1dw_calc(wave + 16, l15, l4);
  const int dw3 = c1dw_calc(wave + 24, l15, l4);
  const int dw4 = c1dw_calc(wave + 32, l15, l4);
  const int dw5 = c1dw_calc(wave + 40, l15, l4);
  const int stb = wave * 128 + l4 * 32 + l15;       // c1 store base; +1024/iter
  const int ba0 = c2ba_calc(wave,      l15);
  const int ba1 = c2ba_calc(wave + 8,  l15);
  const int ba2 = c2ba_calc(wave + 16, l15);
  const int ba3 = c2ba_calc(wave + 24, l15);
  const int st0 = c2st_calc(wave,      l15, l4);
  const int st1 = c2st_calc(wave + 8,  l15, l4);
  const int st2 = c2st_calc(wave + 16, l15, l4);
  const int st3 = c2st_calc(wave + 24, l15, l4);
  __syncthreads();

  // resident B-fragments + per-lane constants
  const half8 cb0 = *(const half8*)(c1B + l15 * 40 + l4 * 8);
  const half8 cb1 = *(const half8*)(c1B + 640 + l15 * 40 + l4 * 8);
  const half8 bw0 = *(const half8*)(w2L + l15 * 104 + 0 + l4 * 8);
  const half8 bw1 = *(const half8*)(w2L + l15 * 104 + 32 + l4 * 8);
  const half8 bw2 = *(const half8*)(w2L + l15 * 104 + 64 + l4 * 8);
  const float b1v = bc1L[l15 & 7];
  const float b2v = bc2L[l15];
  int off0, off1, off2;
  {
    int tap, du, dv;
    tap = l4;     du = (tap >= 6) ? 2 : ((tap >= 3) ? 1 : 0); dv = tap - 3 * du; off0 = (du * 13 + dv) * 16;
    tap = 4 + l4; du = (tap >= 6) ? 2 : ((tap >= 3) ? 1 : 0); dv = tap - 3 * du; off1 = (du * 13 + dv) * 16;
    tap = 8 + l4; du = (tap >= 6) ? 2 : ((tap >= 3) ? 1 : 0); dv = tap - 3 * du; off2 = (du * 13 + dv) * 16;
  }
  const uint32_t* xd = (const uint32_t*)xs;
  const char* pbase = (const char*)p1f;

  auto conv1_body = [&](int dw, int st) {
    union { uint32_t u[4]; half8 h; } ua;
    ua.u[0] = xd[dw]; ua.u[1] = xd[dw + 1];
    ua.u[2] = xd[dw + 20]; ua.u[3] = xd[dw + 21];
    floatx4 ac1 = {0.f, 0.f, 0.f, 0.f}, ac2 = {0.f, 0.f, 0.f, 0.f};
    ac1 = __builtin_amdgcn_mfma_f32_16x16x32_f16(ua.h, cb0, ac1, 0, 0, 0);
    ac2 = __builtin_amdgcn_mfma_f32_16x16x32_f16(ua.h, cb1, ac2, 0, 0, 0);
#pragma unroll
    for (int rr = 0; rr < 4; ++rr) {
      float mx = fmaxf(ac1[rr], ac2[rr]);
      mx = fmaxf(mx, __shfl_xor(mx, 8));
      if (l15 < 8)
        p1f[st + rr * 8] = (_Float16)fmaxf(mx + b1v, 0.f);
    }
  };
  auto conv2_body = [&](int ba, int st) {
    floatx4 acc = {0.f, 0.f, 0.f, 0.f};
    acc = __builtin_amdgcn_mfma_f32_16x16x32_f16(*(const half8*)(pbase + ba + off0), bw0, acc, 0, 0, 0);
    acc = __builtin_amdgcn_mfma_f32_16x16x32_f16(*(const half8*)(pbase + ba + off1), bw1, acc, 0, 0, 0);
    acc = __builtin_amdgcn_mfma_f32_16x16x32_f16(*(const half8*)(pbase + ba + off2), bw2, acc, 0, 0, 0);
    float mx = fmaxf(fmaxf(acc[0], acc[1]), fmaxf(acc[2], acc[3]));
    p2h[st] = (_Float16)fmaxf(mx + b2v, 0.f);
  };

  // ---- conv stages: 4 sub-batches of 4 images ----
  for (int sb = 0; sb < 4; ++sb) {
    conv1_body(dw0, stb);
    conv1_body(dw1, stb + 1024);
    conv1_body(dw2, stb + 2048);
    conv1_body(dw3, stb + 3072);
    conv1_body(dw4, stb + 4096);
    if (wave < 4) conv1_body(dw5, stb + 5120);
    __syncthreads();
    const int sbo = sb * 1696;
    conv2_body(ba0, sbo + st0);
    conv2_body(ba1, sbo + st1);
    conv2_body(ba2, sbo + st2);
    if (wave == 0) conv2_body(ba3, sbo + st3);
    if (sb < 3) {
      *(uint2*)(xs + pfl0) = pkh4(X4[pfg0 + (sb + 1) * 784]);
      if (tid < 272) *(uint2*)(xs + pfl1) = pkh4(X4[pfg1 + (sb + 1) * 784]);
    }
    __syncthreads();
  }

  // ---- stage fc2/fc3 weights (region free now) ----
  {
    int o = tid >> 3, qq = tid & 7;
    const float* src = F2W + (size_t)o * 128 + qq * 16;
    uint2 a = pkh4(*(const float4*)(src));
    uint2 b = pkh4(*(const float4*)(src + 4));
    uint2 c = pkh4(*(const float4*)(src + 8));
    uint2 d = pkh4(*(const float4*)(src + 12));
    *(uint4*)(w2sf + o * 136 + qq * 16) = make_uint4(a.x, a.y, b.x, b.y);
    *(uint4*)(w2sf + o * 136 + qq * 16 + 8) = make_uint4(c.x, c.y, d.x, d.y);
  }
  if (tid < 80) {
    int o = tid / 8, qq = tid & 7;
    const float* src = F3W + o * 64 + qq * 8;
    uint2 a = pkh4(*(const float4*)(src));
    uint2 b = pkh4(*(const float4*)(src + 4));
    *(uint4*)(w3sf + o * 72 + qq * 8) = make_uint4(a.x, a.y, b.x, b.y);
  }

  // ---- fc1: [16 x 416] x [416 x 128], B direct from global (L2), reg dbuf ----
  const int o1 = wave * 16 + l15;
  const float4* FWq = (const float4*)FW;
  const float4 fz = {0.f, 0.f, 0.f, 0.f};
  float4 cur0, cur1, nxt0, nxt1;
  { int kn = l4 * 8;
    cur0 = FWq[(size_t)o1 * 100 + (kn >> 2)];
    cur1 = FWq[(size_t)o1 * 100 + (kn >> 2) + 1]; }
  floatx4 fa = {0.f, 0.f, 0.f, 0.f};
#pragma unroll
  for (int c = 0; c < 13; ++c) {
    if (c < 12) {
      int kn = (c + 1) * 32 + l4 * 8;
      nxt0 = (kn < 400) ? FWq[(size_t)o1 * 100 + (kn >> 2)] : fz;
      nxt1 = (kn + 4 < 400) ? FWq[(size_t)o1 * 100 + (kn >> 2) + 1] : fz;
    }
    half8 a = *(const half8*)(p2h + l15 * 424 + c * 32 + l4 * 8);
    union { uint2 u2[2]; half8 h; } ub;
    ub.u2[0] = pkh4(cur0); ub.u2[1] = pkh4(cur1);
    fa = __builtin_amdgcn_mfma_f32_16x16x32_f16(a, ub.h, fa, 0, 0, 0);
    cur0 = nxt0; cur1 = nxt1;
  }
  __syncthreads();  // p2h reads done (h1f aliases)
  {
    float bia = fbL[o1];
#pragma unroll
    for (int rr = 0; rr < 4; ++rr)
      h1f[(4 * l4 + rr) * 136 + o1] = (_Float16)fmaxf(fa[rr] + bia, 0.f);
  }
  __syncthreads();

  // ---- fc2: [16 x 128] x [128 x 64] on waves 0..3 ----
  if (wave < 4) {
    floatx4 a2 = {0.f, 0.f, 0.f, 0.f};
#pragma unroll
    for (int kt = 0; kt < 4; ++kt) {
      half8 a = *(const half8*)(h1f + l15 * 136 + kt * 32 + l4 * 8);
      half8 b = *(const half8*)(w2sf + (wave * 16 + l15) * 136 + kt * 32 + l4 * 8);
      a2 = __builtin_amdgcn_mfma_f32_16x16x32_f16(a, b, a2, 0, 0, 0);
    }
    float bb = f2bL[wave * 16 + l15];
#pragma unroll
    for (int rr = 0; rr < 4; ++rr)
      h2f[(4 * l4 + rr) * 68 + wave * 16 + l15] = a2[rr] + bb;
  }
  __syncthreads();

  // ---- fc3: 16 x 10, K=64 ----
  if (tid < 160) {
    int img = tid / 10, o = tid - img * 10;
    float s = f3bL[o];
#pragma unroll
    for (int kc = 0; kc < 8; ++kc) {
      half8 wv = *(const half8*)(w3sf + o * 72 + kc * 8);
      float4 hA = *(const float4*)(h2f + img * 68 + kc * 8);
      float4 hB = *(const float4*)(h2f + img * 68 + kc * 8 + 4);
      s += hA.x * (float)wv[0] + hA.y * (float)wv[1] + hA.z * (float)wv[2] + hA.w * (float)wv[3]
         + hB.x * (float)wv[4] + hB.y * (float)wv[5] + hB.z * (float)wv[6] + hB.w * (float)wv[7];
    }
    OUT[(size_t)(m16 + img) * 10 + o] = s;
  }
}

extern "C" void kernel_launch(void* const* d_in, const int* in_sizes, int n_in,
                              void* d_out, int out_size, void* d_ws, size_t ws_size,
                              hipStream_t stream) {
  const float* x   = (const float*)d_in[0];
  const float* c1w = (const float*)d_in[1];
  const float* c1b = (const float*)d_in[2];
  const float* c2w = (const float*)d_in[3];
  const float* c2b = (const float*)d_in[4];
  const float* fw  = (const float*)d_in[5];
  const float* fb  = (const float*)d_in[6];
  const float* f2w = (const float*)d_in[7];
  const float* f2b = (const float*)d_in[8];
  const float* f3w = (const float*)d_in[9];
  const float* f3b = (const float*)d_in[10];
  float* out = (float*)d_out;

  const int B = in_sizes[0] / 784;   // 16384
  lenet_mfma5<<<B / 16, 512, 0, stream>>>(x, c1w, c1b, c2w, c2b,
                                          fw, fb, f2w, f2b, f3w, f3b, out);
}

// Round 13
// 133.230 us; speedup vs baseline: 1.0499x; 1.0499x over previous
//
#include <hip/hip_runtime.h>
#include <hip/hip_bf16.h>

typedef _Float16 half8 __attribute__((ext_vector_type(8)));
typedef __fp16 fp16x2 __attribute__((ext_vector_type(2)));
typedef float floatx4 __attribute__((ext_vector_type(4)));

__device__ __forceinline__ uint2 pkh4(float4 v) {
  union { fp16x2 h2[2]; uint2 u; } pk;
  pk.h2[0] = __builtin_amdgcn_cvt_pkrtz(v.x, v.y);
  pk.h2[1] = __builtin_amdgcn_cvt_pkrtz(v.z, v.w);
  return pk.u;
}

// lane i <- lane (i+8)&15 within each 16-lane row (== lane^8 here): pure-VALU
// cross-lane via DPP row_ror:8 (0x120|8). No lgkmcnt traffic, unlike ds_swizzle.
__device__ __forceinline__ float dpp_ror8_max(float x) {
  int t = __builtin_amdgcn_update_dpp(0, __builtin_bit_cast(int, x),
                                      0x128, 0xf, 0xf, true);
  return fmaxf(x, __builtin_bit_cast(float, t));
}

__device__ __forceinline__ int c1dw_calc(int mt, int l15, int l4) {
  int m = mt * 16 + l15; if (m > 675) m = 675;
  int img = m / 169, rem = m - img * 169, wr = rem / 13, wc = rem - wr * 13;
  int rowa = img * 28 + 2 * wr + 2 * l4; if (rowa > 110) rowa = 110;
  return rowa * 20 + wc;
}
__device__ __forceinline__ int c2ba_calc(int mt, int l15) {
  int w = mt * 4 + (l15 >> 2), q = l15 & 3;
  int img = w / 25, rem = w - img * 25, wr = rem / 5, wc = rem - wr * 5;
  int r = 2 * wr + (q >> 1), c = 2 * wc + (q & 1);
  return (img * 169 + r * 13 + c) * 16;
}
__device__ __forceinline__ int c2st_calc(int mt, int l15, int l4) {
  int w2 = mt * 4 + l4, i2 = w2 / 25, rm2 = w2 - i2 * 25;
  return i2 * 424 + l15 * 25 + rm2;
}

// LeNet fwd, all-MFMA convs, window-ordered M. Named-scalar hoisted indices,
// DPP-based pool combine. 16 img / 512-thr block, 1024 blocks, 4 blk/CU.
__global__ __launch_bounds__(512, 8) void lenet_mfma6(
    const float* __restrict__ X,
    const float* __restrict__ W1, const float* __restrict__ B1,
    const float* __restrict__ W2, const float* __restrict__ B2,
    const float* __restrict__ FW, const float* __restrict__ FB,
    const float* __restrict__ F2W, const float* __restrict__ F2B,
    const float* __restrict__ F3W, const float* __restrict__ F3B,
    float* __restrict__ OUT) {
  __shared__ __align__(16) _Float16 p2h[16 * 424];  // pool2 [16][424], 400.. zero; h1f/h2f alias
  __shared__ __align__(16) char region[20224];      // conv: xs f16[4][28][40] + p1f f16[704][8] | fc: w2sf[64][136]+w3sf[10][72]
  __shared__ __align__(16) _Float16 w2L[16 * 104];  // conv2 B [oc][k=tap*8+ic] zero-pad
  __shared__ __align__(16) _Float16 c1B[1280];      // conv1 B 2x[16][40]
  __shared__ float bc1L[8], bc2L[16], fbL[128], f2bL[64], f3bL[16];

  _Float16* xs = (_Float16*)region;                 // [4][28][40]
  _Float16* p1f = (_Float16*)(region + 8960);       // [704][8]
  _Float16* w2sf = (_Float16*)region;               // [64][136]
  _Float16* w3sf = (_Float16*)(region + 17408);     // [10][72]
  _Float16* h1f = p2h;                              // [16][136]
  float* h2f = (float*)((char*)p2h + 6656);         // [16][68]

  const int tid = threadIdx.x;
  const int wave = tid >> 6, lane = tid & 63, l15 = lane & 15, l4 = lane >> 4;
  const int m16 = blockIdx.x * 16;
  const float4* X4 = (const float4*)X;

  // ---- one-time staging ----
  if (tid < 8) bc1L[tid] = B1[tid];
  else if (tid < 24) bc2L[tid - 8] = B2[tid - 8];
  else if (tid < 152) fbL[tid - 24] = FB[tid - 24];
  else if (tid < 216) f2bL[tid - 152] = F2B[tid - 152];
  else if (tid < 226) f3bL[tid - 216] = F3B[tid - 216];

  for (int i = tid; i < 1664; i += 512) {           // conv2 B
    int oc = i / 104, k = i % 104;
    _Float16 v = (_Float16)0.f;
    if (k < 72) { int tap = k >> 3, ic = k & 7; v = (_Float16)W2[(oc * 8 + ic) * 9 + tap]; }
    w2L[i] = v;
  }
  for (int i = tid; i < 1280; i += 512) {           // conv1 B (2 mats)
    int mat = i / 640, r = i % 640, n = r / 40, k = r % 40;
    float v = 0.f;
    if (k < 16) {
      int q = mat * 2 + (n >> 3), ch = n & 7;
      int uu = (k >> 2) - (q >> 1), vv = (k & 3) - (q & 1);
      if (uu >= 0 && uu < 3 && vv >= 0 && vv < 3) v = W1[ch * 9 + uu * 3 + vv];
    }
    c1B[i] = (_Float16)v;
  }
  if (tid < 384) { int rr = tid / 24; p2h[rr * 424 + 400 + tid % 24] = (_Float16)0.f; }

  // ---- prefetch indices (named scalars) + sb=0 image load ----
  int pfg0, pfl0, pfg1, pfl1;
  {
    int i = tid, img = i / 196, f = i % 196, row = f / 7, fq = f % 7;
    pfg0 = (m16 + img) * 196 + f;
    pfl0 = (img * 28 + row) * 40 + fq * 4;
    int i1 = tid + 512; int i1c = (i1 < 784) ? i1 : 783;
    int img1 = i1c / 196, f1 = i1c % 196, row1 = f1 / 7, fq1 = f1 % 7;
    pfg1 = (m16 + img1) * 196 + f1;
    pfl1 = (img1 * 28 + row1) * 40 + fq1 * 4;
    *(uint2*)(xs + pfl0) = pkh4(X4[pfg0]);
    if (i1 < 784) *(uint2*)(xs + pfl1) = pkh4(X4[pfg1]);
  }

  // ---- conv per-iter indices: NAMED SCALARS (registers, no scratch) ----
  const int dw0 = c1dw_calc(wave,      l15, l4);
  const int dw1 = c1dw_calc(wave + 8,  l15, l4);
  const int dw2 = c1dw_calc(wave + 16, l15, l4);
  const int dw3 = c1dw_calc(wave + 24, l15, l4);
  const int dw4 = c1dw_calc(wave + 32, l15, l4);
  const int dw5 = c1dw_calc(wave + 40, l15, l4);
  const int stb = wave * 128 + l4 * 32 + l15;       // c1 store base; +1024/iter
  const int ba0 = c2ba_calc(wave,      l15);
  const int ba1 = c2ba_calc(wave + 8,  l15);
  const int ba2 = c2ba_calc(wave + 16, l15);
  const int ba3 = c2ba_calc(wave + 24, l15);
  const int st0 = c2st_calc(wave,      l15, l4);
  const int st1 = c2st_calc(wave + 8,  l15, l4);
  const int st2 = c2st_calc(wave + 16, l15, l4);
  const int st3 = c2st_calc(wave + 24, l15, l4);
  __syncthreads();

  // resident B-fragments + per-lane constants
  const half8 cb0 = *(const half8*)(c1B + l15 * 40 + l4 * 8);
  const half8 cb1 = *(const half8*)(c1B + 640 + l15 * 40 + l4 * 8);
  const half8 bw0 = *(const half8*)(w2L + l15 * 104 + 0 + l4 * 8);
  const half8 bw1 = *(const half8*)(w2L + l15 * 104 + 32 + l4 * 8);
  const half8 bw2 = *(const half8*)(w2L + l15 * 104 + 64 + l4 * 8);
  const float b1v = bc1L[l15 & 7];
  const float b2v = bc2L[l15];
  int off0, off1, off2;
  {
    int tap, du, dv;
    tap = l4;     du = (tap >= 6) ? 2 : ((tap >= 3) ? 1 : 0); dv = tap - 3 * du; off0 = (du * 13 + dv) * 16;
    tap = 4 + l4; du = (tap >= 6) ? 2 : ((tap >= 3) ? 1 : 0); dv = tap - 3 * du; off1 = (du * 13 + dv) * 16;
    tap = 8 + l4; du = (tap >= 6) ? 2 : ((tap >= 3) ? 1 : 0); dv = tap - 3 * du; off2 = (du * 13 + dv) * 16;
  }
  const uint32_t* xd = (const uint32_t*)xs;
  const char* pbase = (const char*)p1f;

  auto conv1_body = [&](int dw, int st) {
    union { uint32_t u[4]; half8 h; } ua;
    ua.u[0] = xd[dw]; ua.u[1] = xd[dw + 1];
    ua.u[2] = xd[dw + 20]; ua.u[3] = xd[dw + 21];
    floatx4 ac1 = {0.f, 0.f, 0.f, 0.f}, ac2 = {0.f, 0.f, 0.f, 0.f};
    ac1 = __builtin_amdgcn_mfma_f32_16x16x32_f16(ua.h, cb0, ac1, 0, 0, 0);
    ac2 = __builtin_amdgcn_mfma_f32_16x16x32_f16(ua.h, cb1, ac2, 0, 0, 0);
#pragma unroll
    for (int rr = 0; rr < 4; ++rr) {
      float mx = dpp_ror8_max(fmaxf(ac1[rr], ac2[rr]));   // combine quadrant pair, VALU-only
      if (l15 < 8)
        p1f[st + rr * 8] = (_Float16)fmaxf(mx + b1v, 0.f);
    }
  };
  auto conv2_body = [&](int ba, int st) {
    floatx4 acc = {0.f, 0.f, 0.f, 0.f};
    acc = __builtin_amdgcn_mfma_f32_16x16x32_f16(*(const half8*)(pbase + ba + off0), bw0, acc, 0, 0, 0);
    acc = __builtin_amdgcn_mfma_f32_16x16x32_f16(*(const half8*)(pbase + ba + off1), bw1, acc, 0, 0, 0);
    acc = __builtin_amdgcn_mfma_f32_16x16x32_f16(*(const half8*)(pbase + ba + off2), bw2, acc, 0, 0, 0);
    float mx = fmaxf(fmaxf(acc[0], acc[1]), fmaxf(acc[2], acc[3]));
    p2h[st] = (_Float16)fmaxf(mx + b2v, 0.f);
  };

  // ---- conv stages: 4 sub-batches of 4 images ----
  for (int sb = 0; sb < 4; ++sb) {
    conv1_body(dw0, stb);
    conv1_body(dw1, stb + 1024);
    conv1_body(dw2, stb + 2048);
    conv1_body(dw3, stb + 3072);
    conv1_body(dw4, stb + 4096);
    if (wave < 4) conv1_body(dw5, stb + 5120);
    __syncthreads();
    const int sbo = sb * 1696;
    conv2_body(ba0, sbo + st0);
    conv2_body(ba1, sbo + st1);
    conv2_body(ba2, sbo + st2);
    if (wave == 0) conv2_body(ba3, sbo + st3);
    if (sb < 3) {
      *(uint2*)(xs + pfl0) = pkh4(X4[pfg0 + (sb + 1) * 784]);
      if (tid < 272) *(uint2*)(xs + pfl1) = pkh4(X4[pfg1 + (sb + 1) * 784]);
    }
    __syncthreads();
  }

  // ---- stage fc2/fc3 weights (region free now) ----
  {
    int o = tid >> 3, qq = tid & 7;
    const float* src = F2W + (size_t)o * 128 + qq * 16;
    uint2 a = pkh4(*(const float4*)(src));
    uint2 b = pkh4(*(const float4*)(src + 4));
    uint2 c = pkh4(*(const float4*)(src + 8));
    uint2 d = pkh4(*(const float4*)(src + 12));
    *(uint4*)(w2sf + o * 136 + qq * 16) = make_uint4(a.x, a.y, b.x, b.y);
    *(uint4*)(w2sf + o * 136 + qq * 16 + 8) = make_uint4(c.x, c.y, d.x, d.y);
  }
  if (tid < 80) {
    int o = tid / 8, qq = tid & 7;
    const float* src = F3W + o * 64 + qq * 8;
    uint2 a = pkh4(*(const float4*)(src));
    uint2 b = pkh4(*(const float4*)(src + 4));
    *(uint4*)(w3sf + o * 72 + qq * 8) = make_uint4(a.x, a.y, b.x, b.y);
  }

  // ---- fc1: [16 x 416] x [416 x 128], B direct from global (L2), reg dbuf ----
  const int o1 = wave * 16 + l15;
  const float4* FWq = (const float4*)FW;
  const float4 fz = {0.f, 0.f, 0.f, 0.f};
  float4 cur0, cur1, nxt0, nxt1;
  { int kn = l4 * 8;
    cur0 = FWq[(size_t)o1 * 100 + (kn >> 2)];
    cur1 = FWq[(size_t)o1 * 100 + (kn >> 2) + 1]; }
  floatx4 fa = {0.f, 0.f, 0.f, 0.f};
#pragma unroll
  for (int c = 0; c < 13; ++c) {
    if (c < 12) {
      int kn = (c + 1) * 32 + l4 * 8;
      nxt0 = (kn < 400) ? FWq[(size_t)o1 * 100 + (kn >> 2)] : fz;
      nxt1 = (kn + 4 < 400) ? FWq[(size_t)o1 * 100 + (kn >> 2) + 1] : fz;
    }
    half8 a = *(const half8*)(p2h + l15 * 424 + c * 32 + l4 * 8);
    union { uint2 u2[2]; half8 h; } ub;
    ub.u2[0] = pkh4(cur0); ub.u2[1] = pkh4(cur1);
    fa = __builtin_amdgcn_mfma_f32_16x16x32_f16(a, ub.h, fa, 0, 0, 0);
    cur0 = nxt0; cur1 = nxt1;
  }
  __syncthreads();  // p2h reads done (h1f aliases)
  {
    float bia = fbL[o1];
#pragma unroll
    for (int rr = 0; rr < 4; ++rr)
      h1f[(4 * l4 + rr) * 136 + o1] = (_Float16)fmaxf(fa[rr] + bia, 0.f);
  }
  __syncthreads();

  // ---- fc2: [16 x 128] x [128 x 64] on waves 0..3 ----
  if (wave < 4) {
    floatx4 a2 = {0.f, 0.f, 0.f, 0.f};
#pragma unroll
    for (int kt = 0; kt < 4; ++kt) {
      half8 a = *(const half8*)(h1f + l15 * 136 + kt * 32 + l4 * 8);
      half8 b = *(const half8*)(w2sf + (wave * 16 + l15) * 136 + kt * 32 + l4 * 8);
      a2 = __builtin_amdgcn_mfma_f32_16x16x32_f16(a, b, a2, 0, 0, 0);
    }
    float bb = f2bL[wave * 16 + l15];
#pragma unroll
    for (int rr = 0; rr < 4; ++rr)
      h2f[(4 * l4 + rr) * 68 + wave * 16 + l15] = a2[rr] + bb;
  }
  __syncthreads();

  // ---- fc3: 16 x 10, K=64 ----
  if (tid < 160) {
    int img = tid / 10, o = tid - img * 10;
    float s = f3bL[o];
#pragma unroll
    for (int kc = 0; kc < 8; ++kc) {
      half8 wv = *(const half8*)(w3sf + o * 72 + kc * 8);
      float4 hA = *(const float4*)(h2f + img * 68 + kc * 8);
      float4 hB = *(const float4*)(h2f + img * 68 + kc * 8 + 4);
      s += hA.x * (float)wv[0] + hA.y * (float)wv[1] + hA.z * (float)wv[2] + hA.w * (float)wv[3]
         + hB.x * (float)wv[4] + hB.y * (float)wv[5] + hB.z * (float)wv[6] + hB.w * (float)wv[7];
    }
    OUT[(size_t)(m16 + img) * 10 + o] = s;
  }
}

extern "C" void kernel_launch(void* const* d_in, const int* in_sizes, int n_in,
                              void* d_out, int out_size, void* d_ws, size_t ws_size,
                              hipStream_t stream) {
  const float* x   = (const float*)d_in[0];
  const float* c1w = (const float*)d_in[1];
  const float* c1b = (const float*)d_in[2];
  const float* c2w = (const float*)d_in[3];
  const float* c2b = (const float*)d_in[4];
  const float* fw  = (const float*)d_in[5];
  const float* fb  = (const float*)d_in[6];
  const float* f2w = (const float*)d_in[7];
  const float* f2b = (const float*)d_in[8];
  const float* f3w = (const float*)d_in[9];
  const float* f3b = (const float*)d_in[10];
  float* out = (float*)d_out;

  const int B = in_sizes[0] / 784;   // 16384
  lenet_mfma6<<<B / 16, 512, 0, stream>>>(x, c1w, c1b, c2w, c2b,
                                          fw, fb, f2w, f2b, f3w, f3b, out);
}